// Round 12
// baseline (878.681 us; speedup 1.0000x reference)
//
#include <hip/hip_runtime.h>
#include <hip/hip_bf16.h>
#include <cstdint>

typedef unsigned short u16;
typedef __bf16 bf16x4_t __attribute__((ext_vector_type(4)));
typedef __bf16 bf16x8_t __attribute__((ext_vector_type(8)));
typedef float f32x4_t __attribute__((ext_vector_type(4)));
typedef unsigned short us4_t __attribute__((ext_vector_type(4)));
typedef unsigned short us8_t __attribute__((ext_vector_type(8)));

#define BATCH 2
#define SEQ 1024
#define HID 2048
#define NHEAD 32
#define NEXP 8
#define MDIM 1024
#define T_TOK (BATCH*SEQ)   // 2048

// ---------- helpers ----------

__device__ __forceinline__ void gload16(const void* g, void* l){
  __builtin_amdgcn_global_load_lds((__attribute__((address_space(1))) void*)(uintptr_t)g,
                                   (__attribute__((address_space(3))) void*)l, 16, 0, 0);
}

// Swizzled fragment read, 64B LDS rows (MoE A-side, BK=32): byte ^= (row&3)<<4.
__device__ __forceinline__ bf16x8_t ldfsw64(const u16* base, int row, int colbyte){
  const char* p = (const char*)base + row*64;
  int sw = (row & 3) << 4;
  bf16x4_t a = *(const bf16x4_t*)(p + (colbyte ^ sw));
  bf16x4_t b = *(const bf16x4_t*)(p + ((colbyte + 32) ^ sw));
  return __builtin_shufflevector(a, b, 0,1,2,3,4,5,6,7);
}

__device__ __forceinline__ f32x4_t mfma16(bf16x8_t a, bf16x8_t b, f32x4_t c){
  return __builtin_amdgcn_mfma_f32_16x16x32_bf16(a, b, c, 0, 0, 0);
}

__device__ __forceinline__ u16 f2b(float f){
  __hip_bfloat16 h = __float2bfloat16(f);
  return __builtin_bit_cast(u16, h);
}
__device__ __forceinline__ float b2f(u16 b){
  return __builtin_bit_cast(float, (unsigned int)b << 16);
}
// 3-way bf16 split: v ~= b1 + b2 + b3
__device__ __forceinline__ void split3v(float v, u16& b1, u16& b2, u16& b3){
  b1 = f2b(v); float f1 = b2f(b1);
  float r1 = v - f1;
  b2 = f2b(r1); float f2 = b2f(b2);
  b3 = f2b(r1 - f2);
}

// Standard frag-linear slab (rows x k, k-blocked by 32):
//   rec u16 off = (((row>>7)*KB + kb)*8 + (row>>4)&7)*512 + ((row&15)*4 + fg)*8 + half*4 + e
// Per-head Q/K slab (64 d): off = ((tb*2+kb)*64 + (tok&15)*4 + (d&15)>>2)*8 + ((d>>4)&1)*4 + (d&3)
// Per-head V slab: off = (((tok>>5)*4 + d>>4)*64 + (d&15)*4 + (tok&15)>>2)*8 + ((tok>>4)&1)*4 + (tok&3)

// ---------- MoE weight convert+transpose -> FRAGMENT-LINEAR: f32 [C k][R n] -> slabs ----------

__global__ __launch_bounds__(256)
void convT_fl(const float* __restrict__ in, u16* __restrict__ out, int R, int C)
{
  __shared__ float t[64][65];
  const int KB = C >> 5;
  int bz = blockIdx.z;
  const float* ip = in + (size_t)bz * R * C;
  u16* op = out + (size_t)bz * R * C;
  int r0 = blockIdx.y*64, c0 = blockIdx.x*64;   // r = k dim, c = n dim
  int tid = threadIdx.x;
  int lr = tid >> 4;
  int lc = (tid & 15) * 4;
  #pragma unroll
  for (int i = 0; i < 4; i++){
    int r = lr + i*16;
    float4 v = *(const float4*)&ip[(size_t)(r0 + r) * R + c0 + lc];
    t[r][lc] = v.x; t[r][lc+1] = v.y; t[r][lc+2] = v.z; t[r][lc+3] = v.w;
  }
  __syncthreads();
  if (tid < 128){
    int n_l = tid & 63;
    int kb2 = tid >> 6;
    int gn = c0 + n_l;
    int rb = gn >> 7, sub = (gn >> 4) & 7, frn = gn & 15;
    int kb = (r0 >> 5) + kb2;
    size_t fo = (((size_t)(rb*KB + kb)*8 + sub)*64 + frn*4) * 8;
    #pragma unroll
    for (int fg = 0; fg < 4; fg++){
      us8_t w;
      #pragma unroll
      for (int j = 0; j < 4; j++){
        w[j]   = f2b(t[kb2*32 + fg*4 + j][n_l]);
        w[j+4] = f2b(t[kb2*32 + fg*4 + 16 + j][n_l]);
      }
      *(us8_t*)&op[fo + fg*8] = w;
    }
  }
}

// ---------- attention weight convert+transpose, 3-way split -> standard frag-linear ----------

__global__ __launch_bounds__(256)
void convT3(const float* __restrict__ in, u16* __restrict__ o1, u16* __restrict__ o2,
            u16* __restrict__ o3)
{
  __shared__ float t[64][65];
  int r0 = blockIdx.y*64, c0 = blockIdx.x*64;   // r = k dim, c = n dim
  int tid = threadIdx.x;
  int lr = tid >> 4;
  int lc = (tid & 15) * 4;
  #pragma unroll
  for (int i = 0; i < 4; i++){
    int r = lr + i*16;
    float4 v = *(const float4*)&in[(size_t)(r0 + r) * HID + c0 + lc];
    t[r][lc] = v.x; t[r][lc+1] = v.y; t[r][lc+2] = v.z; t[r][lc+3] = v.w;
  }
  __syncthreads();
  if (tid < 128){
    int n  = tid & 63;
    int kb2 = tid >> 6;
    int gn = c0 + n;
    int nb = gn >> 7, sub = (gn >> 4) & 7, fr = gn & 15;
    int kb = (r0 >> 5) + kb2;
    size_t fo = (((size_t)(nb*64 + kb)*8 + sub)*64 + fr*4) * 8;
    #pragma unroll
    for (int fg = 0; fg < 4; fg++){
      us8_t w1, w2, w3;
      #pragma unroll
      for (int j = 0; j < 4; j++){
        u16 b1, b2, b3;
        split3v(t[kb2*32 + fg*4 + j][n], b1, b2, b3);
        w1[j] = b1; w2[j] = b2; w3[j] = b3;
        split3v(t[kb2*32 + fg*4 + 16 + j][n], b1, b2, b3);
        w1[j+4] = b1; w2[j+4] = b2; w3[j+4] = b3;
      }
      *(us8_t*)&o1[fo + fg*8] = w1;
      *(us8_t*)&o2[fo + fg*8] = w2;
      *(us8_t*)&o3[fo + fg*8] = w3;
    }
  }
}

// ---------- RMSNorm -> 3-way split, standard frag-linear (attention input) ----------

__global__ __launch_bounds__(256)
void rmsnorm3_k(const float* __restrict__ x, const float* __restrict__ w,
                u16* __restrict__ o1, u16* __restrict__ o2, u16* __restrict__ o3)
{
  int row = blockIdx.x;
  const float* xr = x + (size_t)row * HID;
  int tid = threadIdx.x;
  int kb = tid >> 2, fg = tid & 3;
  int kbase = kb*32 + fg*4;
  float4 a = *(const float4*)(xr + kbase);
  float4 b = *(const float4*)(xr + kbase + 16);
  float ss = a.x*a.x + a.y*a.y + a.z*a.z + a.w*a.w
           + b.x*b.x + b.y*b.y + b.z*b.z + b.w*b.w;
  #pragma unroll
  for (int off = 32; off; off >>= 1) ss += __shfl_down(ss, off);
  __shared__ float red[4];
  if ((tid & 63) == 0) red[tid >> 6] = ss;
  __syncthreads();
  float tot = red[0] + red[1] + red[2] + red[3];
  float rs = (float)(1.0 / sqrt((double)tot * (1.0/2048.0) + 1e-5));
  float4 wa = *(const float4*)(w + kbase);
  float4 wb = *(const float4*)(w + kbase + 16);
  float o[8];
  o[0]=a.x*rs*wa.x; o[1]=a.y*rs*wa.y; o[2]=a.z*rs*wa.z; o[3]=a.w*rs*wa.w;
  o[4]=b.x*rs*wb.x; o[5]=b.y*rs*wb.y; o[6]=b.z*rs*wb.z; o[7]=b.w*rs*wb.w;
  us8_t w1, w2, w3;
  #pragma unroll
  for (int j = 0; j < 8; j++){
    u16 b1, b2, b3; split3v(o[j], b1, b2, b3);
    w1[j] = b1; w2[j] = b2; w3[j] = b3;
  }
  int rb = row >> 7, sub = (row >> 4) & 7, fr = row & 15;
  size_t fo = (((size_t)(rb*64 + kb)*8 + sub)*64 + fr*4 + fg) * 8;
  *(us8_t*)&o1[fo] = w1; *(us8_t*)&o2[fo] = w2; *(us8_t*)&o3[fo] = w3;
}

// ---------- RMSNorm (MoE): bf16 out + f32 out + residual passthrough to Out ----------

__global__ __launch_bounds__(256)
void rmsnorm_k(const float* __restrict__ x, const float* __restrict__ w,
               u16* __restrict__ ob, float* __restrict__ of, float* __restrict__ oi)
{
  int row = blockIdx.x;
  const float* xr = x + (size_t)row * HID;
  int base = threadIdx.x * 8;
  float4 a = *(const float4*)(xr + base);
  float4 b = *(const float4*)(xr + base + 4);
  float ss = a.x*a.x + a.y*a.y + a.z*a.z + a.w*a.w
           + b.x*b.x + b.y*b.y + b.z*b.z + b.w*b.w;
  #pragma unroll
  for (int off = 32; off; off >>= 1) ss += __shfl_down(ss, off);
  __shared__ float red[4];
  if ((threadIdx.x & 63) == 0) red[threadIdx.x >> 6] = ss;
  __syncthreads();
  float tot = red[0] + red[1] + red[2] + red[3];
  float rs = (float)(1.0 / sqrt((double)tot * (1.0/2048.0) + 1e-5));
  float4 wa = *(const float4*)(w + base);
  float4 wb = *(const float4*)(w + base + 4);
  float o[8];
  o[0]=a.x*rs*wa.x; o[1]=a.y*rs*wa.y; o[2]=a.z*rs*wa.z; o[3]=a.w*rs*wa.w;
  o[4]=b.x*rs*wb.x; o[5]=b.y*rs*wb.y; o[6]=b.z*rs*wb.z; o[7]=b.w*rs*wb.w;
  us4_t p0, p1;
  p0.x=f2b(o[0]); p0.y=f2b(o[1]); p0.z=f2b(o[2]); p0.w=f2b(o[3]);
  p1.x=f2b(o[4]); p1.y=f2b(o[5]); p1.z=f2b(o[6]); p1.w=f2b(o[7]);
  *(us4_t*)&ob[(size_t)row*HID + base] = p0;
  *(us4_t*)&ob[(size_t)row*HID + base + 4] = p1;
  float* orow = of + (size_t)row*HID + base;
  *(float4*)orow = make_float4(o[0],o[1],o[2],o[3]);
  *(float4*)(orow+4) = make_float4(o[4],o[5],o[6],o[7]);
  float* irow = oi + (size_t)row*HID + base;
  *(float4*)irow = a;
  *(float4*)(irow+4) = b;
}

// ---------- RoPE table (f64 math -> f32) ----------

__global__ void rope_table_k(float* ct, float* st){
  int i = blockIdx.x*256 + threadIdx.x;   // SEQ*32
  int s = i >> 5, j = i & 31;
  double invf = exp(-(double)j / 32.0 * log(10000.0));
  double ang = (double)s * invf;
  ct[i] = (float)cos(ang);
  st[i] = (float)sin(ang);
}

// ---------- fused Q/K/V split GEMM, 64x128 wave tiles (LDS-read intensity fix) ----------
// Block 256 thr = 4 waves (2x2), block tile 128x256, grid (8,16,3)=384 blocks.
// Per-acc 6-product chains identical to previous rounds -> bit-identical output.

__global__ __launch_bounds__(256, 2)
void gemm_qkv(const u16* __restrict__ A1, const u16* __restrict__ A2, const u16* __restrict__ A3,
              const u16* __restrict__ Wq1, const u16* __restrict__ Wq2, const u16* __restrict__ Wq3,
              const u16* __restrict__ Wk1, const u16* __restrict__ Wk2, const u16* __restrict__ Wk3,
              const u16* __restrict__ Wv1, const u16* __restrict__ Wv2, const u16* __restrict__ Wv3,
              u16* __restrict__ oq1, u16* __restrict__ oq2, u16* __restrict__ oq3,
              u16* __restrict__ ok1, u16* __restrict__ ok2, u16* __restrict__ ok3,
              u16* __restrict__ vt1, u16* __restrict__ vt2, u16* __restrict__ vt3,
              const float* __restrict__ ct, const float* __restrict__ st)
{
  __shared__ u16 As[3][4096];      // 24KB: A tile, 128 rows x 32 k, frag-linear
  __shared__ u16 Bs[3][2][4096];   // 48KB: B tile, 256 rows x 32 k
  const int flat = blockIdx.x + 8*blockIdx.y + 128*blockIdx.z;
  const int logical = (flat & 7) * 48 + (flat >> 3);   // XCD-contiguous, bijective over 384
  const int z    = logical >> 7;
  const int rr   = logical & 127;
  const int bm_i = rr >> 3;        // 0..15 (rows of 128)
  const int bn_i = rr & 7;         // 0..7  (cols of 256)
  const int bm = bm_i * 128;
  const int tid = threadIdx.x;
  const int lane = tid & 63;
  const int wave = tid >> 6;
  const int wr = wave >> 1, wc = wave & 1;
  const int fr = lane & 15, fg = lane >> 4;

  f32x4_t acc[4][8] = {};

  const u16* Ap[3] = {A1, A2, A3};
  const u16* Bp[3];
  if (z == 0)      { Bp[0] = Wq1; Bp[1] = Wq2; Bp[2] = Wq3; }
  else if (z == 1) { Bp[0] = Wk1; Bp[1] = Wk2; Bp[2] = Wk3; }
  else             { Bp[0] = Wv1; Bp[1] = Wv2; Bp[2] = Wv3; }
  const u16* gA[3]; const u16* gB0[3]; const u16* gB1[3];
  #pragma unroll
  for (int t = 0; t < 3; t++){
    gA[t]  = Ap[t] + (size_t)bm_i * 262144 + tid*8;
    gB0[t] = Bp[t] + (size_t)(2*bn_i)     * 262144 + tid*8;
    gB1[t] = Bp[t] + (size_t)(2*bn_i + 1) * 262144 + tid*8;
  }

  for (int kb = 0; kb < 64; kb++){
    const size_t o = (size_t)kb * 4096;
    #pragma unroll
    for (int t = 0; t < 3; t++){
      gload16(gA[t]  + o,        &As[t][tid*8]);
      gload16(gA[t]  + o + 2048, &As[t][2048 + tid*8]);
      gload16(gB0[t] + o,        &Bs[t][0][tid*8]);
      gload16(gB0[t] + o + 2048, &Bs[t][0][2048 + tid*8]);
      gload16(gB1[t] + o,        &Bs[t][1][tid*8]);
      gload16(gB1[t] + o + 2048, &Bs[t][1][2048 + tid*8]);
    }
    __syncthreads();
    bf16x8_t af[3][4];
    #pragma unroll
    for (int t = 0; t < 3; t++)
      #pragma unroll
      for (int mi = 0; mi < 4; mi++)
        af[t][mi] = *(const bf16x8_t*)&As[t][(((wr*4 + mi)*64) + fr*4 + fg)*8];
    #pragma unroll
    for (int ni = 0; ni < 8; ni++){
      const int bo = (ni*64 + fr*4 + fg)*8;
      bf16x8_t b1 = *(const bf16x8_t*)&Bs[0][wc][bo];
      bf16x8_t b2 = *(const bf16x8_t*)&Bs[1][wc][bo];
      bf16x8_t b3 = *(const bf16x8_t*)&Bs[2][wc][bo];
      #pragma unroll
      for (int mi = 0; mi < 4; mi++){
        f32x4_t c = acc[mi][ni];
        c = mfma16(af[2][mi], b1, c);   // a3b1
        c = mfma16(af[1][mi], b2, c);   // a2b2
        c = mfma16(af[0][mi], b3, c);   // a1b3
        c = mfma16(af[1][mi], b1, c);   // a2b1
        c = mfma16(af[0][mi], b2, c);   // a1b2
        c = mfma16(af[0][mi], b1, c);   // a1b1
        acc[mi][ni] = c;
      }
    }
    __syncthreads();
  }

  if (z < 2){
    u16* O1 = z ? ok1 : oq1;
    u16* O2 = z ? ok2 : oq2;
    u16* O3 = z ? ok3 : oq3;
    #pragma unroll
    for (int mi = 0; mi < 4; mi++)
      #pragma unroll
      for (int r = 0; r < 4; r++){
        int row = bm + wr*64 + mi*16 + fg*4 + r;
        int s = row & (SEQ-1);
        int b = row >> 10;
        int tok = row & 1023;
        int tb = tok >> 4;
        int frk = fg*4 + r;   // tok & 15
        #pragma unroll
        for (int hh = 0; hh < 2; hh++){
          int h = bn_i*4 + wc*2 + hh;
          size_t sb = (size_t)(b*NHEAD + h) * 65536;
          #pragma unroll
          for (int nip = 0; nip < 2; nip++){
            int nl = hh*4 + nip, nh = nl + 2;
            int dlo = nip*16 + fr;   // 0..31 within head
            float c  = ct[s*32 + dlo];
            float sn = st[s*32 + dlo];
            float xl = acc[mi][nl][r], xh = acc[mi][nh][r];
            float ol = xl*c - xh*sn;   // d = dlo    (kb 0)
            float oh = xh*c + xl*sn;   // d = dlo+32 (kb 1)
            size_t a0 = sb + ((size_t)(tb*2 + 0)*64 + frk*4 + (fr>>2))*8 + nip*4 + (fr&3);
            size_t a1 = sb + ((size_t)(tb*2 + 1)*64 + frk*4 + (fr>>2))*8 + nip*4 + (fr&3);
            u16 b1, b2, b3;
            split3v(ol, b1, b2, b3); O1[a0] = b1; O2[a0] = b2; O3[a0] = b3;
            split3v(oh, b1, b2, b3); O1[a1] = b1; O2[a1] = b2; O3[a1] = b3;
          }
        }
      }
  } else {
    // V: 3-way split directly into per-head frag-linear V slabs
    const int b = bm >> 10;
    const int tokb = (bm & 1023) + wr*64;
    #pragma unroll
    for (int mi = 0; mi < 4; mi++){
      const int kbv = (tokb + mi*16) >> 5;
      const int el = (mi & 1) * 4;
      #pragma unroll
      for (int ni = 0; ni < 8; ni++){
        const int hh = ni >> 2, db = ni & 3;
        const int h = bn_i*4 + wc*2 + hh;
        const size_t sb = (size_t)(b*NHEAD + h) * 65536;
        us4_t v1, v2, v3;
        #pragma unroll
        for (int r = 0; r < 4; r++){
          u16 b1, b2, b3; split3v(acc[mi][ni][r], b1, b2, b3);
          v1[r] = b1; v2[r] = b2; v3[r] = b3;
        }
        size_t a = sb + ((size_t)(kbv*4 + db)*64 + fr*4 + fg)*8 + el;
        *(us4_t*)&vt1[a] = v1; *(us4_t*)&vt2[a] = v2; *(us4_t*)&vt3[a] = v3;
      }
    }
  }
}

// ---------- O-projection split GEMM, 128x64 tiles (frag-linear), +residual ----------

__global__ __launch_bounds__(256, 2)
void gemm_o(const u16* __restrict__ A1, const u16* __restrict__ A2, const u16* __restrict__ A3,
            const u16* __restrict__ B1, const u16* __restrict__ B2, const u16* __restrict__ B3,
            float* __restrict__ Cf, const float* __restrict__ Res)
{
  __shared__ u16 As[3][128*32];   // 24KB
  __shared__ u16 Bs[3][64*32];    // 12KB
  const int flat = blockIdx.x + 32*blockIdx.y;
  const int logical = (flat & 7) * 64 + (flat >> 3);   // 512 = 8*64
  const int bn = (logical & 31) * 64;
  const int bm = (logical >> 5) * 128;
  const int tid = threadIdx.x;
  const int lane = tid & 63;
  const int wave = tid >> 6;
  const int wr = wave >> 1, wc = wave & 1;
  const int fr = lane & 15, fg = lane >> 4;

  f32x4_t acc[4][2] = {};

  const u16* Ap[3] = {A1, A2, A3};
  const u16* Bp[3] = {B1, B2, B3};
  const u16* gA[3]; const u16* gB[3];
  const int sb0 = (bn >> 4) & 7;   // 0 or 4
  #pragma unroll
  for (int t = 0; t < 3; t++){
    gA[t] = Ap[t] + (size_t)(bm >> 7) * 262144 + tid*8;
    gB[t] = Bp[t] + (size_t)(bn >> 7) * 262144 + sb0*512 + tid*8;
  }

  for (int kb = 0; kb < 64; kb++){
    const size_t o = (size_t)kb * 4096;
    #pragma unroll
    for (int t = 0; t < 3; t++){
      gload16(gA[t] + o,        &As[t][tid*8]);
      gload16(gA[t] + o + 2048, &As[t][2048 + tid*8]);
      gload16(gB[t] + o,        &Bs[t][tid*8]);
    }
    __syncthreads();
    bf16x8_t bfv[3][2];
    #pragma unroll
    for (int t = 0; t < 3; t++)
      #pragma unroll
      for (int nj = 0; nj < 2; nj++)
        bfv[t][nj] = *(const bf16x8_t*)&Bs[t][(((wc*2 + nj)*64) + fr*4 + fg)*8];
    #pragma unroll
    for (int mi = 0; mi < 4; mi++){
      const int ao = (((wr*4 + mi)*64) + fr*4 + fg)*8;
      bf16x8_t a1 = *(const bf16x8_t*)&As[0][ao];
      bf16x8_t a2 = *(const bf16x8_t*)&As[1][ao];
      bf16x8_t a3 = *(const bf16x8_t*)&As[2][ao];
      #pragma unroll
      for (int nj = 0; nj < 2; nj++){
        f32x4_t c = acc[mi][nj];
        c = mfma16(a3, bfv[0][nj], c);
        c = mfma16(a2, bfv[1][nj], c);
        c = mfma16(a1, bfv[2][nj], c);
        c = mfma16(a2, bfv[0][nj], c);
        c = mfma16(a1, bfv[1][nj], c);
        c = mfma16(a1, bfv[0][nj], c);
        acc[mi][nj] = c;
      }
    }
    __syncthreads();
  }

  #pragma unroll
  for (int mi = 0; mi < 4; mi++)
    #pragma unroll
    for (int nj = 0; nj < 2; nj++)
      #pragma unroll
      for (int r = 0; r < 4; r++){
        int row = bm + wr*64 + mi*16 + fg*4 + r;
        int col = bn + wc*32 + nj*16 + fr;
        size_t idx = (size_t)row * HID + col;
        Cf[idx] = acc[mi][nj][r] + Res[idx];
      }
}

// ---------- flash attention, split-precision (causal), frag-linear ao out ----------
// Natural grid order (equal-qt batches dispatch together -> balanced).

__global__ __launch_bounds__(256)
void fattn3_k(const u16* __restrict__ q1, const u16* __restrict__ q2, const u16* __restrict__ q3,
              const u16* __restrict__ k1, const u16* __restrict__ k2, const u16* __restrict__ k3,
              const u16* __restrict__ v1, const u16* __restrict__ v2, const u16* __restrict__ v3,
              u16* __restrict__ ao1, u16* __restrict__ ao2, u16* __restrict__ ao3)
{
  __shared__ u16 Ks[3][4096];     // 8KB each
  __shared__ u16 Vs[3][4096];     // 8KB each
  __shared__ u16 Ps[2][4][1024];  // 16KB -> 64KB total
  const int bh = blockIdx.x, qt = blockIdx.y;
  const int b = bh >> 5, h = bh & 31;
  const int tid = threadIdx.x, lane = tid & 63, wave = tid >> 6;
  const int fr = lane & 15, fg = lane >> 4;
  const size_t hslab = (size_t)bh * 65536;

  // Q fragments direct from per-head frag-linear global
  bf16x8_t aq[3][2];
  {
    size_t qo = hslab + (size_t)(qt*4 + wave)*1024 + (size_t)(fr*4 + fg)*8;
    aq[0][0] = *(const bf16x8_t*)&q1[qo]; aq[0][1] = *(const bf16x8_t*)&q1[qo + 512];
    aq[1][0] = *(const bf16x8_t*)&q2[qo]; aq[1][1] = *(const bf16x8_t*)&q2[qo + 512];
    aq[2][0] = *(const bf16x8_t*)&q3[qo]; aq[2][1] = *(const bf16x8_t*)&q3[qo + 512];
  }

  f32x4_t oacc[4] = {};
  float m_r[4], l_r[4];
  #pragma unroll
  for (int r = 0; r < 4; r++){ m_r[r] = -1e30f; l_r[r] = 0.f; }

  const u16* kp[3] = { k1 + hslab, k2 + hslab, k3 + hslab };
  const u16* vp[3] = { v1 + hslab, v2 + hslab, v3 + hslab };

  for (int kt = 0; kt <= qt; kt++){
    const size_t o = (size_t)kt * 4096;
    #pragma unroll
    for (int t = 0; t < 3; t++){
      gload16(kp[t] + o + tid*8,        &Ks[t][tid*8]);
      gload16(kp[t] + o + 2048 + tid*8, &Ks[t][2048 + tid*8]);
      gload16(vp[t] + o + tid*8,        &Vs[t][tid*8]);
      gload16(vp[t] + o + 2048 + tid*8, &Vs[t][2048 + tid*8]);
    }
    __syncthreads();

    f32x4_t sc[4] = {};
    #pragma unroll
    for (int nf = 0; nf < 4; nf++)
      #pragma unroll
      for (int ks = 0; ks < 2; ks++){
        const int ko = ((nf*2 + ks)*64 + fr*4 + fg)*8;
        bf16x8_t bk0 = *(const bf16x8_t*)&Ks[0][ko];
        bf16x8_t bk1 = *(const bf16x8_t*)&Ks[1][ko];
        bf16x8_t bk2 = *(const bf16x8_t*)&Ks[2][ko];
        sc[nf] = mfma16(aq[2][ks], bk0, sc[nf]);
        sc[nf] = mfma16(aq[1][ks], bk1, sc[nf]);
        sc[nf] = mfma16(aq[0][ks], bk2, sc[nf]);
        sc[nf] = mfma16(aq[1][ks], bk0, sc[nf]);
        sc[nf] = mfma16(aq[0][ks], bk1, sc[nf]);
        sc[nf] = mfma16(aq[0][ks], bk0, sc[nf]);
      }

    float nm[4] = {-1e30f,-1e30f,-1e30f,-1e30f};
    #pragma unroll
    for (int nf = 0; nf < 4; nf++)
      #pragma unroll
      for (int r = 0; r < 4; r++){
        float v = sc[nf][r] * 0.125f;
        if (kt == qt && nf*16 + fr > wave*16 + fg*4 + r) v = -1e30f;
        sc[nf][r] = v;
        nm[r] = fmaxf(nm[r], v);
      }
    #pragma unroll
    for (int r = 0; r < 4; r++)
      #pragma unroll
      for (int msk = 8; msk; msk >>= 1) nm[r] = fmaxf(nm[r], __shfl_xor(nm[r], msk));

    #pragma unroll
    for (int r = 0; r < 4; r++){
      float mn = fmaxf(m_r[r], nm[r]);
      float f = __expf(m_r[r] - mn);
      m_r[r] = mn;
      float rsum = 0.f;
      #pragma unroll
      for (int nf = 0; nf < 4; nf++){
        float pv = __expf(sc[nf][r] - mn);
        sc[nf][r] = pv;
        rsum += pv;
      }
      #pragma unroll
      for (int msk = 8; msk; msk >>= 1) rsum += __shfl_xor(rsum, msk);
      l_r[r] = l_r[r]*f + rsum;
      #pragma unroll
      for (int df = 0; df < 4; df++) oacc[df][r] *= f;
    }

    // P 2-way split to frag-linear LDS
    #pragma unroll
    for (int nf = 0; nf < 4; nf++)
      #pragma unroll
      for (int r = 0; r < 4; r++){
        float pv = sc[nf][r];
        u16 b1 = f2b(pv);
        float f1 = b2f(b1);
        u16 b2 = f2b(pv - f1);
        int pa = ((nf>>1)*64 + (fg*4 + r)*4 + (fr>>2))*8 + (nf&1)*4 + (fr&3);
        Ps[0][wave][pa] = b1;
        Ps[1][wave][pa] = b2;
      }

    #pragma unroll
    for (int ks = 0; ks < 2; ks++){
      bf16x8_t pa0 = *(const bf16x8_t*)&Ps[0][wave][(ks*64 + fr*4 + fg)*8];
      bf16x8_t pa1 = *(const bf16x8_t*)&Ps[1][wave][(ks*64 + fr*4 + fg)*8];
      #pragma unroll
      for (int df = 0; df < 4; df++){
        const int vo = ((ks*4 + df)*64 + fr*4 + fg)*8;
        bf16x8_t bv0 = *(const bf16x8_t*)&Vs[0][vo];
        bf16x8_t bv1 = *(const bf16x8_t*)&Vs[1][vo];
        bf16x8_t bv2 = *(const bf16x8_t*)&Vs[2][vo];
        oacc[df] = mfma16(pa0, bv2, oacc[df]);   // p1 v3
        oacc[df] = mfma16(pa1, bv1, oacc[df]);   // p2 v2
        oacc[df] = mfma16(pa1, bv0, oacc[df]);   // p2 v1
        oacc[df] = mfma16(pa0, bv1, oacc[df]);   // p1 v2
        oacc[df] = mfma16(pa0, bv0, oacc[df]);   // p1 v1
      }
    }
    __syncthreads();
  }

  // output: 3-way split directly to standard frag-linear ao slabs
  #pragma unroll
  for (int r = 0; r < 4; r++){
    float inv = 1.f / l_r[r];
    int orow = b*SEQ + qt*64 + wave*16 + fg*4 + r;
    int rb = orow >> 7, sub = (orow >> 4) & 7, frA = orow & 15;
    #pragma unroll
    for (int df = 0; df < 4; df++){
      float val = oacc[df][r] * inv;
      int kb = h*2 + (df >> 1);
      size_t addr = ((((size_t)rb*64 + kb)*8 + sub)*64 + frA*4 + (fr>>2))*8 + (df&1)*4 + (fr&3);
      u16 b1, b2, b3; split3v(val, b1, b2, b3);
      ao1[addr] = b1; ao2[addr] = b2; ao3[addr] = b3;
    }
  }
}

// ---------- router + scatter: f64 logits, top-2, compact per-expert lists ----------

__global__ __launch_bounds__(64)
void router_scatter_k(const float* __restrict__ yn, const float* __restrict__ Wr,
                      int* __restrict__ tok_list, float* __restrict__ w_list,
                      int* __restrict__ cur){
  int row = blockIdx.x;
  int lane = threadIdx.x;
  const float* xr = yn + (size_t)row * HID;
  double acc[8] = {};
  for (int j = lane; j < HID; j += 64){
    double xv = (double)xr[j];
    const float* wr = Wr + (size_t)j*8;
    float4 w0 = *(const float4*)wr;
    float4 w1 = *(const float4*)(wr + 4);
    acc[0] += xv*w0.x; acc[1] += xv*w0.y; acc[2] += xv*w0.z; acc[3] += xv*w0.w;
    acc[4] += xv*w1.x; acc[5] += xv*w1.y; acc[6] += xv*w1.z; acc[7] += xv*w1.w;
  }
  #pragma unroll
  for (int e = 0; e < 8; e++)
    #pragma unroll
    for (int off = 32; off; off >>= 1) acc[e] += __shfl_down(acc[e], off);
  if (lane == 0){
    double mx = acc[0];
    #pragma unroll
    for (int e = 1; e < 8; e++) mx = fmax(mx, acc[e]);
    double p[8];
    #pragma unroll
    for (int e = 0; e < 8; e++) p[e] = exp(acc[e] - mx);
    int i1 = 0;
    #pragma unroll
    for (int e = 1; e < 8; e++) if (p[e] > p[i1]) i1 = e;
    int i2 = (i1 == 0) ? 1 : 0;
    #pragma unroll
    for (int e = 0; e < 8; e++) if (e != i1 && p[e] > p[i2]) i2 = e;
    double s2 = p[i1] + p[i2];
    int pos1 = atomicAdd(&cur[i1], 1);
    tok_list[i1*T_TOK + pos1] = row;
    w_list[i1*T_TOK + pos1] = (float)(p[i1] / s2);
    int pos2 = atomicAdd(&cur[i2], 1);
    tok_list[i2*T_TOK + pos2] = row;
    w_list[i2*T_TOK + pos2] = (float)(p[i2] / s2);
  }
}

// pad each expert's list to a multiple of 128 with (token 0, weight 0)
__global__ __launch_bounds__(128)
void pad_k(const int* __restrict__ cur, int* __restrict__ tok_list,
           float* __restrict__ w_list, int* __restrict__ cnt_pad){
  int e = blockIdx.x;
  int c = cur[e];
  int cp = (c + 127) & ~127;
  for (int i = c + threadIdx.x; i < cp; i += 128){
    tok_list[e*T_TOK + i] = 0;
    w_list[e*T_TOK + i] = 0.f;
  }
  if (threadIdx.x == 0) cnt_pad[e] = cp;
}

// ---------- sparse fused gate+up GEMM (frag-linear B): h = silu(g)*u*w ----------

__global__ __launch_bounds__(256, 2)
void gemm_gateup_sp(const u16* __restrict__ A, const u16* __restrict__ WgT, const u16* __restrict__ WuT,
                    const int* __restrict__ tok_list, const float* __restrict__ w_list,
                    const int* __restrict__ cnt_pad, u16* __restrict__ Hb)
{
  const int e = blockIdx.z;
  const int bm = blockIdx.y * 128;   // position within expert list
  if (bm >= cnt_pad[e]) return;
  __shared__ u16 As[128*32];
  __shared__ u16 Bg[64*32];
  __shared__ u16 Bu[64*32];
  const int tid = threadIdx.x;
  const int lane = tid & 63;
  const int wave = tid >> 6;
  const int wr = wave >> 1, wc = wave & 1;
  const int fr = lane & 15, fg = lane >> 4;
  const int bn = blockIdx.x * 64;    // M cols

  f32x4_t ag[4][2] = {}, au[4][2] = {};

  const int srow = tid >> 2, skb = (tid & 3) ^ (srow & 3);   // swizzled A-source chunk
  const int tok0 = tok_list[e*T_TOK + bm + srow];
  const int tok1 = tok_list[e*T_TOK + bm + srow + 64];
  const u16* ga0 = A + (size_t)tok0 * HID + skb * 8;
  const u16* ga1 = A + (size_t)tok1 * HID + skb * 8;
  const int sub0 = (bn >> 4) & 7;    // 0 or 4
  const u16* gg = WgT + (size_t)e*MDIM*HID + ((size_t)(bn>>7)*512 + sub0)*512 + tid*8;
  const u16* gu = WuT + (size_t)e*MDIM*HID + ((size_t)(bn>>7)*512 + sub0)*512 + tid*8;

  for (int kb = 0; kb < 64; kb++){
    gload16(ga0 + kb*32, &As[tid*8]);
    gload16(ga1 + kb*32, &As[2048 + tid*8]);
    gload16(gg + (size_t)kb*4096, &Bg[tid*8]);
    gload16(gu + (size_t)kb*4096, &Bu[tid*8]);
    __syncthreads();
    bf16x8_t af[4], bg[2], bu[2];
    #pragma unroll
    for (int i = 0; i < 4; i++) af[i] = ldfsw64(As, wr*64 + i*16 + fr, fg*8);
    #pragma unroll
    for (int j = 0; j < 2; j++){
      bg[j] = *(const bf16x8_t*)&Bg[((wc*2 + j)*64 + fr*4 + fg)*8];
      bu[j] = *(const bf16x8_t*)&Bu[((wc*2 + j)*64 + fr*4 + fg)*8];
    }
    #pragma unroll
    for (int mi = 0; mi < 4; mi++)
      #pragma unroll
      for (int nj = 0; nj < 2; nj++){
        ag[mi][nj] = mfma16(af[mi], bg[nj], ag[mi][nj]);
        au[mi][nj] = mfma16(af[mi], bu[nj], au[mi][nj]);
      }
    __syncthreads();
  }

  #pragma unroll
  for (int mi = 0; mi < 4; mi++)
    #pragma unroll
    for (int nj = 0; nj < 2; nj++)
      #pragma unroll
      for (int r = 0; r < 4; r++){
        int pos = bm + wr*64 + mi*16 + fg*4 + r;
        int col = bn + wc*32 + nj*16 + fr;
        float g = ag[mi][nj][r], u = au[mi][nj][r];
        float h = g / (1.0f + __expf(-g)) * u * w_list[e*T_TOK + pos];
        Hb[((size_t)e*T_TOK + pos)*MDIM + col] = f2b(h);
      }
}

// ---------- sparse down GEMM (frag-linear B): atomic-accumulate onto Out ----------

__global__ __launch_bounds__(256, 2)
void gemm_down_sp(const u16* __restrict__ Hb, const u16* __restrict__ WdT,
                  const int* __restrict__ tok_list, const int* __restrict__ cnt_pad,
                  float* __restrict__ Out)
{
  const int e = blockIdx.z;
  const int bm = blockIdx.y * 128;
  if (bm >= cnt_pad[e]) return;
  __shared__ u16 As[128*32];
  __shared__ u16 Bs[128*32];
  const int tid = threadIdx.x;
  const int lane = tid & 63;
  const int wave = tid >> 6;
  const int wr = wave >> 1, wc = wave & 1;
  const int fr = lane & 15, fg = lane >> 4;
  const int bn = blockIdx.x * 128;
  const int srow = tid >> 2, skb = (tid & 3) ^ (srow & 3);

  f32x4_t acc[4][4] = {};

  const u16* A  = Hb  + (size_t)e * T_TOK * MDIM;
  const u16* ga0 = A + (size_t)(bm + srow) * MDIM + skb * 8;
  const u16* gB = WdT + (size_t)e*HID*MDIM + (size_t)(bn>>7)*131072 + tid*8;
  for (int kb = 0; kb < 32; kb++){
    gload16(ga0 + kb*32, &As[tid*8]);
    gload16(ga0 + (size_t)64*MDIM + kb*32, &As[2048 + tid*8]);
    gload16(gB + (size_t)kb*4096,        &Bs[tid*8]);
    gload16(gB + (size_t)kb*4096 + 2048, &Bs[2048 + tid*8]);
    __syncthreads();
    bf16x8_t af[4], bfv[4];
    #pragma unroll
    for (int i = 0; i < 4; i++) af[i]  = ldfsw64(As, wr*64 + i*16 + fr, fg*8);
    #pragma unroll
    for (int i = 0; i < 4; i++) bfv[i] = *(const bf16x8_t*)&Bs[((wc*4 + i)*64 + fr*4 + fg)*8];
    #pragma unroll
    for (int mi = 0; mi < 4; mi++)
      #pragma unroll
      for (int ni = 0; ni < 4; ni++)
        acc[mi][ni] = mfma16(af[mi], bfv[ni], acc[mi][ni]);
    __syncthreads();
  }

  #pragma unroll
  for (int mi = 0; mi < 4; mi++)
    #pragma unroll
    for (int r = 0; r < 4; r++){
      int pos = bm + wr*64 + mi*16 + fg*4 + r;
      int tok = tok_list[e*T_TOK + pos];
      #pragma unroll
      for (int ni = 0; ni < 4; ni++){
        int col = bn + wc*64 + ni*16 + fr;
        atomicAdd(&Out[(size_t)tok * HID + col], acc[mi][ni][r]);
      }
    }
}

// ---------- launch ----------
// Workspace plan (peak ~217 MB):
//   R0  96MB: Wq/Wk/Wv/Wo frag-linear splits -> (after O-proj) WgT/WuT/WdT (frag-linear)
//   R1  24MB: xn1..3 -> ynb(8MB)+yn(16MB f32)
//   R2  24MB: q1..3 (per-head frag-linear) -> hb[0..24MB)
//   R3  24MB: k1..3 (per-head frag-linear) -> hb[24..32MB)
//   R5  24MB: ao1..3 (standard frag-linear, written by fattn)
//   R6  24MB: vt1..3 (per-head frag-linear V, written by gemm_qkv) -> x1(f32)
//   RS: tok_list/w_list/cur/cnt_pad/rope tables

extern "C" void kernel_launch(void* const* d_in, const int* in_sizes, int n_in,
                              void* d_out, int out_size, void* d_ws, size_t ws_size,
                              hipStream_t stream)
{
  const float* hs     = (const float*)d_in[0];
  const float* w_attn = (const float*)d_in[1];
  const float* Wq = (const float*)d_in[2];
  const float* Wk = (const float*)d_in[3];
  const float* Wv = (const float*)d_in[4];
  const float* Wo = (const float*)d_in[5];
  const float* w_moe = (const float*)d_in[6];
  const float* Wr = (const float*)d_in[7];
  const float* Wg = (const float*)d_in[8];
  const float* Wu = (const float*)d_in[9];
  const float* Wd = (const float*)d_in[10];
  float* out = (float*)d_out;
  (void)in_sizes; (void)n_in; (void)out_size; (void)ws_size;

  char* ws = (char*)d_ws;
  const size_t MB = 1024*1024;
  char* R0 = ws;                 // 96 MB
  char* R1 = ws + 96*MB;         // 24 MB
  char* R2 = ws + 120*MB;        // 24 MB
  char* R3 = ws + 144*MB;        // 24 MB
  char* R5 = ws + 168*MB;        // 24 MB (ao)
  char* R6 = ws + 192*MB;        // 24 MB (vt -> x1)
  char* RS = ws + 216*MB;        // small buffers

  const size_t WSLB = (size_t)HID*HID;   // 8 MB slabs
  u16* W0 = (u16*)R0;
  u16 *Wq1 = W0,          *Wq2 = W0 + WSLB,    *Wq3 = W0 + 2*WSLB;
  u16 *Wk1 = W0 + 3*WSLB, *Wk2 = W0 + 4*WSLB,  *Wk3 = W0 + 5*WSLB;
  u16 *Wv1 = W0 + 6*WSLB, *Wv2 = W0 + 7*WSLB,  *Wv3 = W0 + 8*WSLB;
  u16 *Wo1 = W0 + 9*WSLB, *Wo2 = W0 + 10*WSLB, *Wo3 = W0 + 11*WSLB;
  const size_t TSLB = (size_t)T_TOK*HID;
  u16 *xn1 = (u16*)R1, *xn2 = (u16*)R1 + TSLB, *xn3 = (u16*)R1 + 2*TSLB;
  u16 *q1  = (u16*)R2, *q2  = (u16*)R2 + TSLB, *q3  = (u16*)R2 + 2*TSLB;
  u16 *k1  = (u16*)R3, *k2  = (u16*)R3 + TSLB, *k3  = (u16*)R3 + 2*TSLB;
  u16 *ao1 = (u16*)R5, *ao2 = (u16*)R5 + TSLB, *ao3 = (u16*)R5 + 2*TSLB;
  u16 *vt1 = (u16*)R6, *vt2 = (u16*)R6 + TSLB, *vt3 = (u16*)R6 + 2*TSLB;
  float* x1  = (float*)R6;                        // reuse after fattn (vt dead)
  // phase B pointers (MoE)
  u16* WgT = (u16*)R0;
  u16* WuT = (u16*)R0 + (size_t)NEXP*MDIM*HID;
  u16* WdT = (u16*)R0 + 2*(size_t)NEXP*MDIM*HID;
  u16* ynb = (u16*)R1;
  float* yn = (float*)(R1 + 8*MB);
  u16* hb  = (u16*)R2;                            // 32 MB spans R2 + first 8MB of R3
  int*   tok_list = (int*)RS;
  float* w_list   = (float*)(RS + 64*1024);
  int*   cur      = (int*)(RS + 128*1024);
  int*   cnt_pad  = (int*)(RS + 132*1024);
  float* ct   = (float*)(RS + 256*1024);
  float* stab = (float*)(RS + 384*1024);

  dim3 blk256(256), gMoE(16,16,8);

  rope_table_k<<<dim3(SEQ*32/256), blk256, 0, stream>>>(ct, stab);
  convT3<<<dim3(HID/64, HID/64), blk256, 0, stream>>>(Wq, Wq1, Wq2, Wq3);
  convT3<<<dim3(HID/64, HID/64), blk256, 0, stream>>>(Wk, Wk1, Wk2, Wk3);
  convT3<<<dim3(HID/64, HID/64), blk256, 0, stream>>>(Wv, Wv1, Wv2, Wv3);
  convT3<<<dim3(HID/64, HID/64), blk256, 0, stream>>>(Wo, Wo1, Wo2, Wo3);

  rmsnorm3_k<<<dim3(T_TOK), blk256, 0, stream>>>(hs, w_attn, xn1, xn2, xn3);

  // fused Q/K/V, 128x256 block tiles, 384 blocks all co-resident
  gemm_qkv<<<dim3(8,16,3), blk256, 0, stream>>>(xn1,xn2,xn3,
      Wq1,Wq2,Wq3, Wk1,Wk2,Wk3, Wv1,Wv2,Wv3,
      q1,q2,q3, k1,k2,k3, vt1,vt2,vt3, ct, stab);

  fattn3_k<<<dim3(64, 16), blk256, 0, stream>>>(q1,q2,q3, k1,k2,k3,
      vt1,vt2,vt3, ao1,ao2,ao3);

  gemm_o<<<dim3(32,16), blk256, 0, stream>>>(ao1,ao2,ao3, Wo1,Wo2,Wo3, x1, hs);  // vt dead

  // attention weights dead -> convert MoE weights (frag-linear) into R0
  convT_fl<<<dim3(MDIM/64, HID/64, NEXP), blk256, 0, stream>>>(Wg, WgT, MDIM, HID);
  convT_fl<<<dim3(MDIM/64, HID/64, NEXP), blk256, 0, stream>>>(Wu, WuT, MDIM, HID);
  convT_fl<<<dim3(HID/64, MDIM/64, NEXP), blk256, 0, stream>>>(Wd, WdT, HID, MDIM);

  rmsnorm_k<<<dim3(T_TOK), blk256, 0, stream>>>(x1, w_moe, ynb, yn, out);   // xn dead

  hipMemsetAsync(cur, 0, NEXP*sizeof(int), stream);
  router_scatter_k<<<dim3(T_TOK), dim3(64), 0, stream>>>(yn, Wr, tok_list, w_list, cur);
  pad_k<<<dim3(NEXP), dim3(128), 0, stream>>>(cur, tok_list, w_list, cnt_pad);

  gemm_gateup_sp<<<gMoE, blk256, 0, stream>>>(ynb, WgT, WuT, tok_list, w_list, cnt_pad, hb);  // q dead
  gemm_down_sp<<<gMoE, blk256, 0, stream>>>(hb, WdT, tok_list, cnt_pad, out);
}

// Round 13
// 836.382 us; speedup vs baseline: 1.0506x; 1.0506x over previous
//
#include <hip/hip_runtime.h>
#include <hip/hip_bf16.h>
#include <cstdint>

typedef unsigned short u16;
typedef __bf16 bf16x4_t __attribute__((ext_vector_type(4)));
typedef __bf16 bf16x8_t __attribute__((ext_vector_type(8)));
typedef float f32x4_t __attribute__((ext_vector_type(4)));
typedef unsigned short us4_t __attribute__((ext_vector_type(4)));
typedef unsigned short us8_t __attribute__((ext_vector_type(8)));

#define BATCH 2
#define SEQ 1024
#define HID 2048
#define NHEAD 32
#define NEXP 8
#define MDIM 1024
#define T_TOK (BATCH*SEQ)   // 2048

// ---------- helpers ----------

__device__ __forceinline__ void gload16(const void* g, void* l){
  __builtin_amdgcn_global_load_lds((__attribute__((address_space(1))) void*)(uintptr_t)g,
                                   (__attribute__((address_space(3))) void*)l, 16, 0, 0);
}

// Swizzled fragment read, 64B LDS rows (MoE A-side, BK=32): byte ^= (row&3)<<4.
__device__ __forceinline__ bf16x8_t ldfsw64(const u16* base, int row, int colbyte){
  const char* p = (const char*)base + row*64;
  int sw = (row & 3) << 4;
  bf16x4_t a = *(const bf16x4_t*)(p + (colbyte ^ sw));
  bf16x4_t b = *(const bf16x4_t*)(p + ((colbyte + 32) ^ sw));
  return __builtin_shufflevector(a, b, 0,1,2,3,4,5,6,7);
}

__device__ __forceinline__ f32x4_t mfma16(bf16x8_t a, bf16x8_t b, f32x4_t c){
  return __builtin_amdgcn_mfma_f32_16x16x32_bf16(a, b, c, 0, 0, 0);
}

__device__ __forceinline__ u16 f2b(float f){
  __hip_bfloat16 h = __float2bfloat16(f);
  return __builtin_bit_cast(u16, h);
}
__device__ __forceinline__ float b2f(u16 b){
  return __builtin_bit_cast(float, (unsigned int)b << 16);
}
// 3-way bf16 split: v ~= b1 + b2 + b3
__device__ __forceinline__ void split3v(float v, u16& b1, u16& b2, u16& b3){
  b1 = f2b(v); float f1 = b2f(b1);
  float r1 = v - f1;
  b2 = f2b(r1); float f2 = b2f(b2);
  b3 = f2b(r1 - f2);
}

// Standard frag-linear slab (rows x k, k-blocked by 32):
//   rec u16 off = (((row>>7)*KB + kb)*8 + (row>>4)&7)*512 + ((row&15)*4 + fg)*8 + half*4 + e
// Per-head Q/K slab (64 d): off = ((tb*2+kb)*64 + (tok&15)*4 + (d&15)>>2)*8 + ((d>>4)&1)*4 + (d&3)
// Per-head V slab: off = (((tok>>5)*4 + d>>4)*64 + (d&15)*4 + (tok&15)>>2)*8 + ((tok>>4)&1)*4 + (tok&3)

// ---------- MoE weight convert+transpose -> FRAGMENT-LINEAR: f32 [C k][R n] -> slabs ----------

__global__ __launch_bounds__(256)
void convT_fl(const float* __restrict__ in, u16* __restrict__ out, int R, int C)
{
  __shared__ float t[64][65];
  const int KB = C >> 5;
  int bz = blockIdx.z;
  const float* ip = in + (size_t)bz * R * C;
  u16* op = out + (size_t)bz * R * C;
  int r0 = blockIdx.y*64, c0 = blockIdx.x*64;   // r = k dim, c = n dim
  int tid = threadIdx.x;
  int lr = tid >> 4;
  int lc = (tid & 15) * 4;
  #pragma unroll
  for (int i = 0; i < 4; i++){
    int r = lr + i*16;
    float4 v = *(const float4*)&ip[(size_t)(r0 + r) * R + c0 + lc];
    t[r][lc] = v.x; t[r][lc+1] = v.y; t[r][lc+2] = v.z; t[r][lc+3] = v.w;
  }
  __syncthreads();
  if (tid < 128){
    int n_l = tid & 63;
    int kb2 = tid >> 6;
    int gn = c0 + n_l;
    int rb = gn >> 7, sub = (gn >> 4) & 7, frn = gn & 15;
    int kb = (r0 >> 5) + kb2;
    size_t fo = (((size_t)(rb*KB + kb)*8 + sub)*64 + frn*4) * 8;
    #pragma unroll
    for (int fg = 0; fg < 4; fg++){
      us8_t w;
      #pragma unroll
      for (int j = 0; j < 4; j++){
        w[j]   = f2b(t[kb2*32 + fg*4 + j][n_l]);
        w[j+4] = f2b(t[kb2*32 + fg*4 + 16 + j][n_l]);
      }
      *(us8_t*)&op[fo + fg*8] = w;
    }
  }
}

// ---------- attention weight convert+transpose, 3-way split -> standard frag-linear ----------

__global__ __launch_bounds__(256)
void convT3(const float* __restrict__ in, u16* __restrict__ o1, u16* __restrict__ o2,
            u16* __restrict__ o3)
{
  __shared__ float t[64][65];
  int r0 = blockIdx.y*64, c0 = blockIdx.x*64;   // r = k dim, c = n dim
  int tid = threadIdx.x;
  int lr = tid >> 4;
  int lc = (tid & 15) * 4;
  #pragma unroll
  for (int i = 0; i < 4; i++){
    int r = lr + i*16;
    float4 v = *(const float4*)&in[(size_t)(r0 + r) * HID + c0 + lc];
    t[r][lc] = v.x; t[r][lc+1] = v.y; t[r][lc+2] = v.z; t[r][lc+3] = v.w;
  }
  __syncthreads();
  if (tid < 128){
    int n  = tid & 63;
    int kb2 = tid >> 6;
    int gn = c0 + n;
    int nb = gn >> 7, sub = (gn >> 4) & 7, fr = gn & 15;
    int kb = (r0 >> 5) + kb2;
    size_t fo = (((size_t)(nb*64 + kb)*8 + sub)*64 + fr*4) * 8;
    #pragma unroll
    for (int fg = 0; fg < 4; fg++){
      us8_t w1, w2, w3;
      #pragma unroll
      for (int j = 0; j < 4; j++){
        u16 b1, b2, b3;
        split3v(t[kb2*32 + fg*4 + j][n], b1, b2, b3);
        w1[j] = b1; w2[j] = b2; w3[j] = b3;
        split3v(t[kb2*32 + fg*4 + 16 + j][n], b1, b2, b3);
        w1[j+4] = b1; w2[j+4] = b2; w3[j+4] = b3;
      }
      *(us8_t*)&o1[fo + fg*8] = w1;
      *(us8_t*)&o2[fo + fg*8] = w2;
      *(us8_t*)&o3[fo + fg*8] = w3;
    }
  }
}

// ---------- RMSNorm -> 3-way split, standard frag-linear (attention input) ----------

__global__ __launch_bounds__(256)
void rmsnorm3_k(const float* __restrict__ x, const float* __restrict__ w,
                u16* __restrict__ o1, u16* __restrict__ o2, u16* __restrict__ o3)
{
  int row = blockIdx.x;
  const float* xr = x + (size_t)row * HID;
  int tid = threadIdx.x;
  int kb = tid >> 2, fg = tid & 3;
  int kbase = kb*32 + fg*4;
  float4 a = *(const float4*)(xr + kbase);
  float4 b = *(const float4*)(xr + kbase + 16);
  float ss = a.x*a.x + a.y*a.y + a.z*a.z + a.w*a.w
           + b.x*b.x + b.y*b.y + b.z*b.z + b.w*b.w;
  #pragma unroll
  for (int off = 32; off; off >>= 1) ss += __shfl_down(ss, off);
  __shared__ float red[4];
  if ((tid & 63) == 0) red[tid >> 6] = ss;
  __syncthreads();
  float tot = red[0] + red[1] + red[2] + red[3];
  float rs = (float)(1.0 / sqrt((double)tot * (1.0/2048.0) + 1e-5));
  float4 wa = *(const float4*)(w + kbase);
  float4 wb = *(const float4*)(w + kbase + 16);
  float o[8];
  o[0]=a.x*rs*wa.x; o[1]=a.y*rs*wa.y; o[2]=a.z*rs*wa.z; o[3]=a.w*rs*wa.w;
  o[4]=b.x*rs*wb.x; o[5]=b.y*rs*wb.y; o[6]=b.z*rs*wb.z; o[7]=b.w*rs*wb.w;
  us8_t w1, w2, w3;
  #pragma unroll
  for (int j = 0; j < 8; j++){
    u16 b1, b2, b3; split3v(o[j], b1, b2, b3);
    w1[j] = b1; w2[j] = b2; w3[j] = b3;
  }
  int rb = row >> 7, sub = (row >> 4) & 7, fr = row & 15;
  size_t fo = (((size_t)(rb*64 + kb)*8 + sub)*64 + fr*4 + fg) * 8;
  *(us8_t*)&o1[fo] = w1; *(us8_t*)&o2[fo] = w2; *(us8_t*)&o3[fo] = w3;
}

// ---------- RMSNorm (MoE): bf16 out + f32 out + residual passthrough to Out ----------

__global__ __launch_bounds__(256)
void rmsnorm_k(const float* __restrict__ x, const float* __restrict__ w,
               u16* __restrict__ ob, float* __restrict__ of, float* __restrict__ oi)
{
  int row = blockIdx.x;
  const float* xr = x + (size_t)row * HID;
  int base = threadIdx.x * 8;
  float4 a = *(const float4*)(xr + base);
  float4 b = *(const float4*)(xr + base + 4);
  float ss = a.x*a.x + a.y*a.y + a.z*a.z + a.w*a.w
           + b.x*b.x + b.y*b.y + b.z*b.z + b.w*b.w;
  #pragma unroll
  for (int off = 32; off; off >>= 1) ss += __shfl_down(ss, off);
  __shared__ float red[4];
  if ((threadIdx.x & 63) == 0) red[threadIdx.x >> 6] = ss;
  __syncthreads();
  float tot = red[0] + red[1] + red[2] + red[3];
  float rs = (float)(1.0 / sqrt((double)tot * (1.0/2048.0) + 1e-5));
  float4 wa = *(const float4*)(w + base);
  float4 wb = *(const float4*)(w + base + 4);
  float o[8];
  o[0]=a.x*rs*wa.x; o[1]=a.y*rs*wa.y; o[2]=a.z*rs*wa.z; o[3]=a.w*rs*wa.w;
  o[4]=b.x*rs*wb.x; o[5]=b.y*rs*wb.y; o[6]=b.z*rs*wb.z; o[7]=b.w*rs*wb.w;
  us4_t p0, p1;
  p0.x=f2b(o[0]); p0.y=f2b(o[1]); p0.z=f2b(o[2]); p0.w=f2b(o[3]);
  p1.x=f2b(o[4]); p1.y=f2b(o[5]); p1.z=f2b(o[6]); p1.w=f2b(o[7]);
  *(us4_t*)&ob[(size_t)row*HID + base] = p0;
  *(us4_t*)&ob[(size_t)row*HID + base + 4] = p1;
  float* orow = of + (size_t)row*HID + base;
  *(float4*)orow = make_float4(o[0],o[1],o[2],o[3]);
  *(float4*)(orow+4) = make_float4(o[4],o[5],o[6],o[7]);
  float* irow = oi + (size_t)row*HID + base;
  *(float4*)irow = a;
  *(float4*)(irow+4) = b;
}

// ---------- RoPE table (f64 math -> f32) ----------

__global__ void rope_table_k(float* ct, float* st){
  int i = blockIdx.x*256 + threadIdx.x;   // SEQ*32
  int s = i >> 5, j = i & 31;
  double invf = exp(-(double)j / 32.0 * log(10000.0));
  double ang = (double)s * invf;
  ct[i] = (float)cos(ang);
  st[i] = (float)sin(ang);
}

// ---------- fused Q/K/V split GEMM (frag-linear in; Q/K/V out per-head frag-linear) ----------
// R11 config: 128x128 block tiles, grid (16,16,3), 48KB LDS, 2 blocks/CU. Best measured (236us).

__global__ __launch_bounds__(256, 2)
void gemm_qkv(const u16* __restrict__ A1, const u16* __restrict__ A2, const u16* __restrict__ A3,
              const u16* __restrict__ Wq1, const u16* __restrict__ Wq2, const u16* __restrict__ Wq3,
              const u16* __restrict__ Wk1, const u16* __restrict__ Wk2, const u16* __restrict__ Wk3,
              const u16* __restrict__ Wv1, const u16* __restrict__ Wv2, const u16* __restrict__ Wv3,
              u16* __restrict__ oq1, u16* __restrict__ oq2, u16* __restrict__ oq3,
              u16* __restrict__ ok1, u16* __restrict__ ok2, u16* __restrict__ ok3,
              u16* __restrict__ vt1, u16* __restrict__ vt2, u16* __restrict__ vt3,
              const float* __restrict__ ct, const float* __restrict__ st)
{
  __shared__ u16 As[3][128*32];
  __shared__ u16 Bs[3][128*32];
  const int flat = blockIdx.x + 16*blockIdx.y + 256*blockIdx.z;
  const int logical = (flat & 7) * 96 + (flat >> 3);   // XCD-contiguous chunks
  const int z  = logical >> 8;
  const int bm = ((logical >> 4) & 15) * 128;
  const int bn = (logical & 15) * 128;
  const int tid = threadIdx.x;
  const int lane = tid & 63;
  const int wave = tid >> 6;
  const int wr = wave >> 1, wc = wave & 1;
  const int fr = lane & 15, fg = lane >> 4;

  f32x4_t acc[4][4] = {};

  const u16* Ap[3] = {A1, A2, A3};
  const u16* Bp[3];
  if (z == 0)      { Bp[0] = Wq1; Bp[1] = Wq2; Bp[2] = Wq3; }
  else if (z == 1) { Bp[0] = Wk1; Bp[1] = Wk2; Bp[2] = Wk3; }
  else             { Bp[0] = Wv1; Bp[1] = Wv2; Bp[2] = Wv3; }
  const u16* gA[3]; const u16* gB[3];
  #pragma unroll
  for (int t = 0; t < 3; t++){
    gA[t] = Ap[t] + (size_t)(bm >> 7) * 262144 + tid*8;
    gB[t] = Bp[t] + (size_t)(bn >> 7) * 262144 + tid*8;
  }

  for (int kb = 0; kb < 64; kb++){
    const size_t o = (size_t)kb * 4096;
    #pragma unroll
    for (int t = 0; t < 3; t++){
      gload16(gA[t] + o,        &As[t][tid*8]);
      gload16(gA[t] + o + 2048, &As[t][2048 + tid*8]);
      gload16(gB[t] + o,        &Bs[t][tid*8]);
      gload16(gB[t] + o + 2048, &Bs[t][2048 + tid*8]);
    }
    __syncthreads();
    bf16x8_t bfv[3][4];
    #pragma unroll
    for (int t = 0; t < 3; t++)
      #pragma unroll
      for (int ni = 0; ni < 4; ni++)
        bfv[t][ni] = *(const bf16x8_t*)&Bs[t][(((wc*4 + ni)*64) + fr*4 + fg)*8];
    #pragma unroll
    for (int mi = 0; mi < 4; mi++){
      const int ao = (((wr*4 + mi)*64) + fr*4 + fg)*8;
      bf16x8_t a1 = *(const bf16x8_t*)&As[0][ao];
      bf16x8_t a2 = *(const bf16x8_t*)&As[1][ao];
      bf16x8_t a3 = *(const bf16x8_t*)&As[2][ao];
      #pragma unroll
      for (int ni = 0; ni < 4; ni++){
        f32x4_t c = acc[mi][ni];
        c = mfma16(a3, bfv[0][ni], c);   // a3b1
        c = mfma16(a2, bfv[1][ni], c);   // a2b2
        c = mfma16(a1, bfv[2][ni], c);   // a1b3
        c = mfma16(a2, bfv[0][ni], c);   // a2b1
        c = mfma16(a1, bfv[1][ni], c);   // a1b2
        c = mfma16(a1, bfv[0][ni], c);   // a1b1
        acc[mi][ni] = c;
      }
    }
    __syncthreads();
  }

  if (z < 2){
    u16* O1 = z ? ok1 : oq1;
    u16* O2 = z ? ok2 : oq2;
    u16* O3 = z ? ok3 : oq3;
    const int h = (bn + wc*64) >> 6;
    #pragma unroll
    for (int mi = 0; mi < 4; mi++)
      #pragma unroll
      for (int r = 0; r < 4; r++){
        int row = bm + wr*64 + mi*16 + fg*4 + r;
        int s = row & (SEQ-1);
        int b = row >> 10;
        int tok = row & 1023;
        int tb = tok >> 4;
        int frk = fg*4 + r;   // tok & 15
        size_t sb = (size_t)(b*NHEAD + h) * 65536;
        #pragma unroll
        for (int ni = 0; ni < 2; ni++){
          int dlo = ni*16 + fr;   // 0..31 within head
          float c  = ct[s*32 + dlo];
          float sn = st[s*32 + dlo];
          float xl = acc[mi][ni][r], xh = acc[mi][ni+2][r];
          float ol = xl*c - xh*sn;   // d = dlo   (kb 0)
          float oh = xh*c + xl*sn;   // d = dlo+32 (kb 1)
          size_t a0 = sb + ((size_t)(tb*2 + 0)*64 + frk*4 + (fr>>2))*8 + ni*4 + (fr&3);
          size_t a1 = sb + ((size_t)(tb*2 + 1)*64 + frk*4 + (fr>>2))*8 + ni*4 + (fr&3);
          u16 b1, b2, b3;
          split3v(ol, b1, b2, b3); O1[a0] = b1; O2[a0] = b2; O3[a0] = b3;
          split3v(oh, b1, b2, b3); O1[a1] = b1; O2[a1] = b2; O3[a1] = b3;
        }
      }
  } else {
    // V: 3-way split directly into per-head frag-linear V slabs
    const int h = (bn + wc*64) >> 6;
    const int b = bm >> 10;
    const size_t sb = (size_t)(b*NHEAD + h) * 65536;
    const int tokb = (bm & 1023) + wr*64;
    #pragma unroll
    for (int mi = 0; mi < 4; mi++){
      const int kbv = (tokb + mi*16) >> 5;
      const int el = (mi & 1) * 4;
      #pragma unroll
      for (int ni = 0; ni < 4; ni++){
        us4_t v1, v2, v3;
        #pragma unroll
        for (int r = 0; r < 4; r++){
          u16 b1, b2, b3; split3v(acc[mi][ni][r], b1, b2, b3);
          v1[r] = b1; v2[r] = b2; v3[r] = b3;
        }
        size_t a = sb + ((size_t)(kbv*4 + ni)*64 + fr*4 + fg)*8 + el;
        *(us4_t*)&vt1[a] = v1; *(us4_t*)&vt2[a] = v2; *(us4_t*)&vt3[a] = v3;
      }
    }
  }
}

// ---------- O-projection split GEMM, 128x64 tiles (frag-linear), +residual ----------

__global__ __launch_bounds__(256, 2)
void gemm_o(const u16* __restrict__ A1, const u16* __restrict__ A2, const u16* __restrict__ A3,
            const u16* __restrict__ B1, const u16* __restrict__ B2, const u16* __restrict__ B3,
            float* __restrict__ Cf, const float* __restrict__ Res)
{
  __shared__ u16 As[3][128*32];   // 24KB
  __shared__ u16 Bs[3][64*32];    // 12KB
  const int flat = blockIdx.x + 32*blockIdx.y;
  const int logical = (flat & 7) * 64 + (flat >> 3);   // 512 = 8*64
  const int bn = (logical & 31) * 64;
  const int bm = (logical >> 5) * 128;
  const int tid = threadIdx.x;
  const int lane = tid & 63;
  const int wave = tid >> 6;
  const int wr = wave >> 1, wc = wave & 1;
  const int fr = lane & 15, fg = lane >> 4;

  f32x4_t acc[4][2] = {};

  const u16* Ap[3] = {A1, A2, A3};
  const u16* Bp[3] = {B1, B2, B3};
  const u16* gA[3]; const u16* gB[3];
  const int sb0 = (bn >> 4) & 7;   // 0 or 4
  #pragma unroll
  for (int t = 0; t < 3; t++){
    gA[t] = Ap[t] + (size_t)(bm >> 7) * 262144 + tid*8;
    gB[t] = Bp[t] + (size_t)(bn >> 7) * 262144 + sb0*512 + tid*8;
  }

  for (int kb = 0; kb < 64; kb++){
    const size_t o = (size_t)kb * 4096;
    #pragma unroll
    for (int t = 0; t < 3; t++){
      gload16(gA[t] + o,        &As[t][tid*8]);
      gload16(gA[t] + o + 2048, &As[t][2048 + tid*8]);
      gload16(gB[t] + o,        &Bs[t][tid*8]);
    }
    __syncthreads();
    bf16x8_t bfv[3][2];
    #pragma unroll
    for (int t = 0; t < 3; t++)
      #pragma unroll
      for (int nj = 0; nj < 2; nj++)
        bfv[t][nj] = *(const bf16x8_t*)&Bs[t][(((wc*2 + nj)*64) + fr*4 + fg)*8];
    #pragma unroll
    for (int mi = 0; mi < 4; mi++){
      const int ao = (((wr*4 + mi)*64) + fr*4 + fg)*8;
      bf16x8_t a1 = *(const bf16x8_t*)&As[0][ao];
      bf16x8_t a2 = *(const bf16x8_t*)&As[1][ao];
      bf16x8_t a3 = *(const bf16x8_t*)&As[2][ao];
      #pragma unroll
      for (int nj = 0; nj < 2; nj++){
        f32x4_t c = acc[mi][nj];
        c = mfma16(a3, bfv[0][nj], c);
        c = mfma16(a2, bfv[1][nj], c);
        c = mfma16(a1, bfv[2][nj], c);
        c = mfma16(a2, bfv[0][nj], c);
        c = mfma16(a1, bfv[1][nj], c);
        c = mfma16(a1, bfv[0][nj], c);
        acc[mi][nj] = c;
      }
    }
    __syncthreads();
  }

  #pragma unroll
  for (int mi = 0; mi < 4; mi++)
    #pragma unroll
    for (int nj = 0; nj < 2; nj++)
      #pragma unroll
      for (int r = 0; r < 4; r++){
        int row = bm + wr*64 + mi*16 + fg*4 + r;
        int col = bn + wc*32 + nj*16 + fr;
        size_t idx = (size_t)row * HID + col;
        Cf[idx] = acc[mi][nj][r] + Res[idx];
      }
}

// ---------- flash attention, split-precision (causal), frag-linear ao out ----------
// Natural grid order (equal-qt batches dispatch together -> balanced).

__global__ __launch_bounds__(256)
void fattn3_k(const u16* __restrict__ q1, const u16* __restrict__ q2, const u16* __restrict__ q3,
              const u16* __restrict__ k1, const u16* __restrict__ k2, const u16* __restrict__ k3,
              const u16* __restrict__ v1, const u16* __restrict__ v2, const u16* __restrict__ v3,
              u16* __restrict__ ao1, u16* __restrict__ ao2, u16* __restrict__ ao3)
{
  __shared__ u16 Ks[3][4096];     // 8KB each
  __shared__ u16 Vs[3][4096];     // 8KB each
  __shared__ u16 Ps[2][4][1024];  // 16KB -> 64KB total
  const int bh = blockIdx.x, qt = blockIdx.y;
  const int b = bh >> 5, h = bh & 31;
  const int tid = threadIdx.x, lane = tid & 63, wave = tid >> 6;
  const int fr = lane & 15, fg = lane >> 4;
  const size_t hslab = (size_t)bh * 65536;

  // Q fragments direct from per-head frag-linear global
  bf16x8_t aq[3][2];
  {
    size_t qo = hslab + (size_t)(qt*4 + wave)*1024 + (size_t)(fr*4 + fg)*8;
    aq[0][0] = *(const bf16x8_t*)&q1[qo]; aq[0][1] = *(const bf16x8_t*)&q1[qo + 512];
    aq[1][0] = *(const bf16x8_t*)&q2[qo]; aq[1][1] = *(const bf16x8_t*)&q2[qo + 512];
    aq[2][0] = *(const bf16x8_t*)&q3[qo]; aq[2][1] = *(const bf16x8_t*)&q3[qo + 512];
  }

  f32x4_t oacc[4] = {};
  float m_r[4], l_r[4];
  #pragma unroll
  for (int r = 0; r < 4; r++){ m_r[r] = -1e30f; l_r[r] = 0.f; }

  const u16* kp[3] = { k1 + hslab, k2 + hslab, k3 + hslab };
  const u16* vp[3] = { v1 + hslab, v2 + hslab, v3 + hslab };

  for (int kt = 0; kt <= qt; kt++){
    const size_t o = (size_t)kt * 4096;
    #pragma unroll
    for (int t = 0; t < 3; t++){
      gload16(kp[t] + o + tid*8,        &Ks[t][tid*8]);
      gload16(kp[t] + o + 2048 + tid*8, &Ks[t][2048 + tid*8]);
      gload16(vp[t] + o + tid*8,        &Vs[t][tid*8]);
      gload16(vp[t] + o + 2048 + tid*8, &Vs[t][2048 + tid*8]);
    }
    __syncthreads();

    f32x4_t sc[4] = {};
    #pragma unroll
    for (int nf = 0; nf < 4; nf++)
      #pragma unroll
      for (int ks = 0; ks < 2; ks++){
        const int ko = ((nf*2 + ks)*64 + fr*4 + fg)*8;
        bf16x8_t bk0 = *(const bf16x8_t*)&Ks[0][ko];
        bf16x8_t bk1 = *(const bf16x8_t*)&Ks[1][ko];
        bf16x8_t bk2 = *(const bf16x8_t*)&Ks[2][ko];
        sc[nf] = mfma16(aq[2][ks], bk0, sc[nf]);
        sc[nf] = mfma16(aq[1][ks], bk1, sc[nf]);
        sc[nf] = mfma16(aq[0][ks], bk2, sc[nf]);
        sc[nf] = mfma16(aq[1][ks], bk0, sc[nf]);
        sc[nf] = mfma16(aq[0][ks], bk1, sc[nf]);
        sc[nf] = mfma16(aq[0][ks], bk0, sc[nf]);
      }

    float nm[4] = {-1e30f,-1e30f,-1e30f,-1e30f};
    #pragma unroll
    for (int nf = 0; nf < 4; nf++)
      #pragma unroll
      for (int r = 0; r < 4; r++){
        float v = sc[nf][r] * 0.125f;
        if (kt == qt && nf*16 + fr > wave*16 + fg*4 + r) v = -1e30f;
        sc[nf][r] = v;
        nm[r] = fmaxf(nm[r], v);
      }
    #pragma unroll
    for (int r = 0; r < 4; r++)
      #pragma unroll
      for (int msk = 8; msk; msk >>= 1) nm[r] = fmaxf(nm[r], __shfl_xor(nm[r], msk));

    #pragma unroll
    for (int r = 0; r < 4; r++){
      float mn = fmaxf(m_r[r], nm[r]);
      float f = __expf(m_r[r] - mn);
      m_r[r] = mn;
      float rsum = 0.f;
      #pragma unroll
      for (int nf = 0; nf < 4; nf++){
        float pv = __expf(sc[nf][r] - mn);
        sc[nf][r] = pv;
        rsum += pv;
      }
      #pragma unroll
      for (int msk = 8; msk; msk >>= 1) rsum += __shfl_xor(rsum, msk);
      l_r[r] = l_r[r]*f + rsum;
      #pragma unroll
      for (int df = 0; df < 4; df++) oacc[df][r] *= f;
    }

    // P 2-way split to frag-linear LDS
    #pragma unroll
    for (int nf = 0; nf < 4; nf++)
      #pragma unroll
      for (int r = 0; r < 4; r++){
        float pv = sc[nf][r];
        u16 b1 = f2b(pv);
        float f1 = b2f(b1);
        u16 b2 = f2b(pv - f1);
        int pa = ((nf>>1)*64 + (fg*4 + r)*4 + (fr>>2))*8 + (nf&1)*4 + (fr&3);
        Ps[0][wave][pa] = b1;
        Ps[1][wave][pa] = b2;
      }

    #pragma unroll
    for (int ks = 0; ks < 2; ks++){
      bf16x8_t pa0 = *(const bf16x8_t*)&Ps[0][wave][(ks*64 + fr*4 + fg)*8];
      bf16x8_t pa1 = *(const bf16x8_t*)&Ps[1][wave][(ks*64 + fr*4 + fg)*8];
      #pragma unroll
      for (int df = 0; df < 4; df++){
        const int vo = ((ks*4 + df)*64 + fr*4 + fg)*8;
        bf16x8_t bv0 = *(const bf16x8_t*)&Vs[0][vo];
        bf16x8_t bv1 = *(const bf16x8_t*)&Vs[1][vo];
        bf16x8_t bv2 = *(const bf16x8_t*)&Vs[2][vo];
        oacc[df] = mfma16(pa0, bv2, oacc[df]);   // p1 v3
        oacc[df] = mfma16(pa1, bv1, oacc[df]);   // p2 v2
        oacc[df] = mfma16(pa1, bv0, oacc[df]);   // p2 v1
        oacc[df] = mfma16(pa0, bv1, oacc[df]);   // p1 v2
        oacc[df] = mfma16(pa0, bv0, oacc[df]);   // p1 v1
      }
    }
    __syncthreads();
  }

  // output: 3-way split directly to standard frag-linear ao slabs
  #pragma unroll
  for (int r = 0; r < 4; r++){
    float inv = 1.f / l_r[r];
    int orow = b*SEQ + qt*64 + wave*16 + fg*4 + r;
    int rb = orow >> 7, sub = (orow >> 4) & 7, frA = orow & 15;
    #pragma unroll
    for (int df = 0; df < 4; df++){
      float val = oacc[df][r] * inv;
      int kb = h*2 + (df >> 1);
      size_t addr = ((((size_t)rb*64 + kb)*8 + sub)*64 + frA*4 + (fr>>2))*8 + (df&1)*4 + (fr&3);
      u16 b1, b2, b3; split3v(val, b1, b2, b3);
      ao1[addr] = b1; ao2[addr] = b2; ao3[addr] = b3;
    }
  }
}

// ---------- router + scatter: f64 logits, top-2, compact per-expert lists ----------

__global__ __launch_bounds__(64)
void router_scatter_k(const float* __restrict__ yn, const float* __restrict__ Wr,
                      int* __restrict__ tok_list, float* __restrict__ w_list,
                      int* __restrict__ cur){
  int row = blockIdx.x;
  int lane = threadIdx.x;
  const float* xr = yn + (size_t)row * HID;
  double acc[8] = {};
  for (int j = lane; j < HID; j += 64){
    double xv = (double)xr[j];
    const float* wr = Wr + (size_t)j*8;
    float4 w0 = *(const float4*)wr;
    float4 w1 = *(const float4*)(wr + 4);
    acc[0] += xv*w0.x; acc[1] += xv*w0.y; acc[2] += xv*w0.z; acc[3] += xv*w0.w;
    acc[4] += xv*w1.x; acc[5] += xv*w1.y; acc[6] += xv*w1.z; acc[7] += xv*w1.w;
  }
  #pragma unroll
  for (int e = 0; e < 8; e++)
    #pragma unroll
    for (int off = 32; off; off >>= 1) acc[e] += __shfl_down(acc[e], off);
  if (lane == 0){
    double mx = acc[0];
    #pragma unroll
    for (int e = 1; e < 8; e++) mx = fmax(mx, acc[e]);
    double p[8];
    #pragma unroll
    for (int e = 0; e < 8; e++) p[e] = exp(acc[e] - mx);
    int i1 = 0;
    #pragma unroll
    for (int e = 1; e < 8; e++) if (p[e] > p[i1]) i1 = e;
    int i2 = (i1 == 0) ? 1 : 0;
    #pragma unroll
    for (int e = 0; e < 8; e++) if (e != i1 && p[e] > p[i2]) i2 = e;
    double s2 = p[i1] + p[i2];
    int pos1 = atomicAdd(&cur[i1], 1);
    tok_list[i1*T_TOK + pos1] = row;
    w_list[i1*T_TOK + pos1] = (float)(p[i1] / s2);
    int pos2 = atomicAdd(&cur[i2], 1);
    tok_list[i2*T_TOK + pos2] = row;
    w_list[i2*T_TOK + pos2] = (float)(p[i2] / s2);
  }
}

// pad each expert's list to a multiple of 128 with (token 0, weight 0)
__global__ __launch_bounds__(128)
void pad_k(const int* __restrict__ cur, int* __restrict__ tok_list,
           float* __restrict__ w_list, int* __restrict__ cnt_pad){
  int e = blockIdx.x;
  int c = cur[e];
  int cp = (c + 127) & ~127;
  for (int i = c + threadIdx.x; i < cp; i += 128){
    tok_list[e*T_TOK + i] = 0;
    w_list[e*T_TOK + i] = 0.f;
  }
  if (threadIdx.x == 0) cnt_pad[e] = cp;
}

// ---------- sparse fused gate+up GEMM (frag-linear B): h = silu(g)*u*w ----------

__global__ __launch_bounds__(256, 2)
void gemm_gateup_sp(const u16* __restrict__ A, const u16* __restrict__ WgT, const u16* __restrict__ WuT,
                    const int* __restrict__ tok_list, const float* __restrict__ w_list,
                    const int* __restrict__ cnt_pad, u16* __restrict__ Hb)
{
  const int e = blockIdx.z;
  const int bm = blockIdx.y * 128;   // position within expert list
  if (bm >= cnt_pad[e]) return;
  __shared__ u16 As[128*32];
  __shared__ u16 Bg[64*32];
  __shared__ u16 Bu[64*32];
  const int tid = threadIdx.x;
  const int lane = tid & 63;
  const int wave = tid >> 6;
  const int wr = wave >> 1, wc = wave & 1;
  const int fr = lane & 15, fg = lane >> 4;
  const int bn = blockIdx.x * 64;    // M cols

  f32x4_t ag[4][2] = {}, au[4][2] = {};

  const int srow = tid >> 2, skb = (tid & 3) ^ (srow & 3);   // swizzled A-source chunk
  const int tok0 = tok_list[e*T_TOK + bm + srow];
  const int tok1 = tok_list[e*T_TOK + bm + srow + 64];
  const u16* ga0 = A + (size_t)tok0 * HID + skb * 8;
  const u16* ga1 = A + (size_t)tok1 * HID + skb * 8;
  const int sub0 = (bn >> 4) & 7;    // 0 or 4
  const u16* gg = WgT + (size_t)e*MDIM*HID + ((size_t)(bn>>7)*512 + sub0)*512 + tid*8;
  const u16* gu = WuT + (size_t)e*MDIM*HID + ((size_t)(bn>>7)*512 + sub0)*512 + tid*8;

  for (int kb = 0; kb < 64; kb++){
    gload16(ga0 + kb*32, &As[tid*8]);
    gload16(ga1 + kb*32, &As[2048 + tid*8]);
    gload16(gg + (size_t)kb*4096, &Bg[tid*8]);
    gload16(gu + (size_t)kb*4096, &Bu[tid*8]);
    __syncthreads();
    bf16x8_t af[4], bg[2], bu[2];
    #pragma unroll
    for (int i = 0; i < 4; i++) af[i] = ldfsw64(As, wr*64 + i*16 + fr, fg*8);
    #pragma unroll
    for (int j = 0; j < 2; j++){
      bg[j] = *(const bf16x8_t*)&Bg[((wc*2 + j)*64 + fr*4 + fg)*8];
      bu[j] = *(const bf16x8_t*)&Bu[((wc*2 + j)*64 + fr*4 + fg)*8];
    }
    #pragma unroll
    for (int mi = 0; mi < 4; mi++)
      #pragma unroll
      for (int nj = 0; nj < 2; nj++){
        ag[mi][nj] = mfma16(af[mi], bg[nj], ag[mi][nj]);
        au[mi][nj] = mfma16(af[mi], bu[nj], au[mi][nj]);
      }
    __syncthreads();
  }

  #pragma unroll
  for (int mi = 0; mi < 4; mi++)
    #pragma unroll
    for (int nj = 0; nj < 2; nj++)
      #pragma unroll
      for (int r = 0; r < 4; r++){
        int pos = bm + wr*64 + mi*16 + fg*4 + r;
        int col = bn + wc*32 + nj*16 + fr;
        float g = ag[mi][nj][r], u = au[mi][nj][r];
        float h = g / (1.0f + __expf(-g)) * u * w_list[e*T_TOK + pos];
        Hb[((size_t)e*T_TOK + pos)*MDIM + col] = f2b(h);
      }
}

// ---------- sparse down GEMM (frag-linear B): atomic-accumulate onto Out ----------

__global__ __launch_bounds__(256, 2)
void gemm_down_sp(const u16* __restrict__ Hb, const u16* __restrict__ WdT,
                  const int* __restrict__ tok_list, const int* __restrict__ cnt_pad,
                  float* __restrict__ Out)
{
  const int e = blockIdx.z;
  const int bm = blockIdx.y * 128;
  if (bm >= cnt_pad[e]) return;
  __shared__ u16 As[128*32];
  __shared__ u16 Bs[128*32];
  const int tid = threadIdx.x;
  const int lane = tid & 63;
  const int wave = tid >> 6;
  const int wr = wave >> 1, wc = wave & 1;
  const int fr = lane & 15, fg = lane >> 4;
  const int bn = blockIdx.x * 128;
  const int srow = tid >> 2, skb = (tid & 3) ^ (srow & 3);

  f32x4_t acc[4][4] = {};

  const u16* A  = Hb  + (size_t)e * T_TOK * MDIM;
  const u16* ga0 = A + (size_t)(bm + srow) * MDIM + skb * 8;
  const u16* gB = WdT + (size_t)e*HID*MDIM + (size_t)(bn>>7)*131072 + tid*8;
  for (int kb = 0; kb < 32; kb++){
    gload16(ga0 + kb*32, &As[tid*8]);
    gload16(ga0 + (size_t)64*MDIM + kb*32, &As[2048 + tid*8]);
    gload16(gB + (size_t)kb*4096,        &Bs[tid*8]);
    gload16(gB + (size_t)kb*4096 + 2048, &Bs[2048 + tid*8]);
    __syncthreads();
    bf16x8_t af[4], bfv[4];
    #pragma unroll
    for (int i = 0; i < 4; i++) af[i]  = ldfsw64(As, wr*64 + i*16 + fr, fg*8);
    #pragma unroll
    for (int i = 0; i < 4; i++) bfv[i] = *(const bf16x8_t*)&Bs[((wc*4 + i)*64 + fr*4 + fg)*8];
    #pragma unroll
    for (int mi = 0; mi < 4; mi++)
      #pragma unroll
      for (int ni = 0; ni < 4; ni++)
        acc[mi][ni] = mfma16(af[mi], bfv[ni], acc[mi][ni]);
    __syncthreads();
  }

  #pragma unroll
  for (int mi = 0; mi < 4; mi++)
    #pragma unroll
    for (int r = 0; r < 4; r++){
      int pos = bm + wr*64 + mi*16 + fg*4 + r;
      int tok = tok_list[e*T_TOK + pos];
      #pragma unroll
      for (int ni = 0; ni < 4; ni++){
        int col = bn + wc*64 + ni*16 + fr;
        atomicAdd(&Out[(size_t)tok * HID + col], acc[mi][ni][r]);
      }
    }
}

// ---------- launch ----------
// Workspace plan (peak ~217 MB):
//   R0  96MB: Wq/Wk/Wv/Wo frag-linear splits -> (after O-proj) WgT/WuT/WdT (frag-linear)
//   R1  24MB: xn1..3 -> ynb(8MB)+yn(16MB f32)
//   R2  24MB: q1..3 (per-head frag-linear) -> hb[0..24MB)
//   R3  24MB: k1..3 (per-head frag-linear) -> hb[24..32MB)
//   R5  24MB: ao1..3 (standard frag-linear, written by fattn)
//   R6  24MB: vt1..3 (per-head frag-linear V, written by gemm_qkv) -> x1(f32)
//   RS: tok_list/w_list/cur/cnt_pad/rope tables

extern "C" void kernel_launch(void* const* d_in, const int* in_sizes, int n_in,
                              void* d_out, int out_size, void* d_ws, size_t ws_size,
                              hipStream_t stream)
{
  const float* hs     = (const float*)d_in[0];
  const float* w_attn = (const float*)d_in[1];
  const float* Wq = (const float*)d_in[2];
  const float* Wk = (const float*)d_in[3];
  const float* Wv = (const float*)d_in[4];
  const float* Wo = (const float*)d_in[5];
  const float* w_moe = (const float*)d_in[6];
  const float* Wr = (const float*)d_in[7];
  const float* Wg = (const float*)d_in[8];
  const float* Wu = (const float*)d_in[9];
  const float* Wd = (const float*)d_in[10];
  float* out = (float*)d_out;
  (void)in_sizes; (void)n_in; (void)out_size; (void)ws_size;

  char* ws = (char*)d_ws;
  const size_t MB = 1024*1024;
  char* R0 = ws;                 // 96 MB
  char* R1 = ws + 96*MB;         // 24 MB
  char* R2 = ws + 120*MB;        // 24 MB
  char* R3 = ws + 144*MB;        // 24 MB
  char* R5 = ws + 168*MB;        // 24 MB (ao)
  char* R6 = ws + 192*MB;        // 24 MB (vt -> x1)
  char* RS = ws + 216*MB;        // small buffers

  const size_t WSLB = (size_t)HID*HID;   // 8 MB slabs
  u16* W0 = (u16*)R0;
  u16 *Wq1 = W0,          *Wq2 = W0 + WSLB,    *Wq3 = W0 + 2*WSLB;
  u16 *Wk1 = W0 + 3*WSLB, *Wk2 = W0 + 4*WSLB,  *Wk3 = W0 + 5*WSLB;
  u16 *Wv1 = W0 + 6*WSLB, *Wv2 = W0 + 7*WSLB,  *Wv3 = W0 + 8*WSLB;
  u16 *Wo1 = W0 + 9*WSLB, *Wo2 = W0 + 10*WSLB, *Wo3 = W0 + 11*WSLB;
  const size_t TSLB = (size_t)T_TOK*HID;
  u16 *xn1 = (u16*)R1, *xn2 = (u16*)R1 + TSLB, *xn3 = (u16*)R1 + 2*TSLB;
  u16 *q1  = (u16*)R2, *q2  = (u16*)R2 + TSLB, *q3  = (u16*)R2 + 2*TSLB;
  u16 *k1  = (u16*)R3, *k2  = (u16*)R3 + TSLB, *k3  = (u16*)R3 + 2*TSLB;
  u16 *ao1 = (u16*)R5, *ao2 = (u16*)R5 + TSLB, *ao3 = (u16*)R5 + 2*TSLB;
  u16 *vt1 = (u16*)R6, *vt2 = (u16*)R6 + TSLB, *vt3 = (u16*)R6 + 2*TSLB;
  float* x1  = (float*)R6;                        // reuse after fattn (vt dead)
  // phase B pointers (MoE)
  u16* WgT = (u16*)R0;
  u16* WuT = (u16*)R0 + (size_t)NEXP*MDIM*HID;
  u16* WdT = (u16*)R0 + 2*(size_t)NEXP*MDIM*HID;
  u16* ynb = (u16*)R1;
  float* yn = (float*)(R1 + 8*MB);
  u16* hb  = (u16*)R2;                            // 32 MB spans R2 + first 8MB of R3
  int*   tok_list = (int*)RS;
  float* w_list   = (float*)(RS + 64*1024);
  int*   cur      = (int*)(RS + 128*1024);
  int*   cnt_pad  = (int*)(RS + 132*1024);
  float* ct   = (float*)(RS + 256*1024);
  float* stab = (float*)(RS + 384*1024);

  dim3 blk256(256), gMoE(16,16,8);

  rope_table_k<<<dim3(SEQ*32/256), blk256, 0, stream>>>(ct, stab);
  convT3<<<dim3(HID/64, HID/64), blk256, 0, stream>>>(Wq, Wq1, Wq2, Wq3);
  convT3<<<dim3(HID/64, HID/64), blk256, 0, stream>>>(Wk, Wk1, Wk2, Wk3);
  convT3<<<dim3(HID/64, HID/64), blk256, 0, stream>>>(Wv, Wv1, Wv2, Wv3);
  convT3<<<dim3(HID/64, HID/64), blk256, 0, stream>>>(Wo, Wo1, Wo2, Wo3);

  rmsnorm3_k<<<dim3(T_TOK), blk256, 0, stream>>>(hs, w_attn, xn1, xn2, xn3);

  // fused Q/K/V (R11 config: 768 blocks, 2/CU, V epilogue fused)
  gemm_qkv<<<dim3(16,16,3), blk256, 0, stream>>>(xn1,xn2,xn3,
      Wq1,Wq2,Wq3, Wk1,Wk2,Wk3, Wv1,Wv2,Wv3,
      q1,q2,q3, k1,k2,k3, vt1,vt2,vt3, ct, stab);

  fattn3_k<<<dim3(64, 16), blk256, 0, stream>>>(q1,q2,q3, k1,k2,k3,
      vt1,vt2,vt3, ao1,ao2,ao3);

  gemm_o<<<dim3(32,16), blk256, 0, stream>>>(ao1,ao2,ao3, Wo1,Wo2,Wo3, x1, hs);  // vt dead

  // attention weights dead -> convert MoE weights (frag-linear) into R0
  convT_fl<<<dim3(MDIM/64, HID/64, NEXP), blk256, 0, stream>>>(Wg, WgT, MDIM, HID);
  convT_fl<<<dim3(MDIM/64, HID/64, NEXP), blk256, 0, stream>>>(Wu, WuT, MDIM, HID);
  convT_fl<<<dim3(HID/64, MDIM/64, NEXP), blk256, 0, stream>>>(Wd, WdT, HID, MDIM);

  rmsnorm_k<<<dim3(T_TOK), blk256, 0, stream>>>(x1, w_moe, ynb, yn, out);   // xn dead

  hipMemsetAsync(cur, 0, NEXP*sizeof(int), stream);
  router_scatter_k<<<dim3(T_TOK), dim3(64), 0, stream>>>(yn, Wr, tok_list, w_list, cur);
  pad_k<<<dim3(NEXP), dim3(128), 0, stream>>>(cur, tok_list, w_list, cnt_pad);

  gemm_gateup_sp<<<gMoE, blk256, 0, stream>>>(ynb, WgT, WuT, tok_list, w_list, cnt_pad, hb);  // q dead
  gemm_down_sp<<<gMoE, blk256, 0, stream>>>(hb, WdT, tok_list, cnt_pad, out);
}